// Round 5
// baseline (238.220 us; speedup 1.0000x reference)
//
#include <hip/hip_runtime.h>
#include <stdint.h>

#define B_   2
#define N_   16384
#define S_   4096
#define D2_  256
#define CIN_ 397
#define KP_  416      // Cin padded to 13*32 for MFMA K-slabs
#define C_   128
#define OC_  13
#define NCHUNK_ 16
#define CHS_ (S_ / NCHUNK_)       // 256 points per scan chunk
#define NCAND_ (NCHUNK_ * 3)      // 48 candidates per query
#define XBI_P 296                 // xbi LDS pitch (u16): 148 words, 2-way banks

typedef unsigned short u16;
typedef unsigned int u32;
typedef short s16x8 __attribute__((ext_vector_type(8)));
typedef float f32x4 __attribute__((ext_vector_type(4)));

#define MFMA16(a, b, c) __builtin_amdgcn_mfma_f32_16x16x32_bf16((a), (b), (c), 0, 0, 0)

__device__ __forceinline__ float b2f(u16 h) {
  union { unsigned int u; float f; } v; v.u = ((unsigned int)h) << 16; return v.f;
}
__device__ __forceinline__ u16 f2b(float f) {
  union { float f; unsigned int u; } v; v.f = f;
  unsigned int r = v.u + 0x7fffu + ((v.u >> 16) & 1u);
  return (u16)(r >> 16);
}

// ---------------------------------------------------------------------------
// prep: convert all weights f32->bf16 (pad fuse_W to [128][416], pred2_W to
// [16][128]) and fold BN+bias into per-channel (scale, bias) in f32.
// ---------------------------------------------------------------------------
__global__ void prep_kernel(const float* __restrict__ fW, const float* __restrict__ fb,
                            const float* __restrict__ fbn,
                            const float* __restrict__ e1W, const float* __restrict__ e1b,
                            const float* __restrict__ e1bn,
                            const float* __restrict__ e2W, const float* __restrict__ e2b,
                            const float* __restrict__ e2bn,
                            const float* __restrict__ p1W, const float* __restrict__ p1b,
                            const float* __restrict__ p1bn,
                            const float* __restrict__ p2W, const float* __restrict__ p2b,
                            const float* __restrict__ p2bn,
                            u16* __restrict__ Wf, u16* __restrict__ W1o,
                            u16* __restrict__ W2o, u16* __restrict__ W3o,
                            u16* __restrict__ Wp2, float* __restrict__ st) {
  int tid = blockIdx.x * 256 + threadIdx.x;
  int stride = gridDim.x * 256;
  for (int i = tid; i < 128 * KP_; i += stride) {
    int m = i / KP_, k = i - m * KP_;
    Wf[i] = (k < CIN_) ? f2b(fW[m * CIN_ + k]) : (u16)0;
  }
  for (int i = tid; i < 128 * 128; i += stride) {
    W1o[i] = f2b(e1W[i]);
    W2o[i] = f2b(e2W[i]);
    W3o[i] = f2b(p1W[i]);
  }
  for (int i = tid; i < 16 * 128; i += stride) {
    int m = i >> 7;
    Wp2[i] = (m < OC_) ? f2b(p2W[i]) : (u16)0;
  }
  for (int i = tid; i < 5 * 128; i += stride) {
    int sg = i >> 7, c = i & 127;
    const float* bn; const float* bc; int Cc = 128;
    switch (sg) {
      case 0: bn = fbn;  bc = fb;  break;
      case 1: bn = e1bn; bc = e1b; break;
      case 2: bn = e2bn; bc = e2b; break;
      case 3: bn = p1bn; bc = p1b; break;
      default: bn = p2bn; bc = p2b; Cc = OC_; break;
    }
    float s = 0.f, t = 0.f;
    if (c < Cc) {
      float g  = bn[0 * Cc + c], be = bn[1 * Cc + c];
      float mu = bn[2 * Cc + c], vv = bn[3 * Cc + c];
      float inv = 1.0f / sqrtf(vv + 1e-5f);
      s = g * inv;
      t = (bc[c] - mu) * s + be;
    }
    st[sg * 256 + c] = s;
    st[sg * 256 + 128 + c] = t;
  }
}

// ---------------------------------------------------------------------------
// tiled transpose, f32 in [b][C][S] -> bf16 out [b][S][opitch] (cols [0,C))
// ---------------------------------------------------------------------------
__global__ void transpose_f2b_kernel(const float* __restrict__ in, u16* __restrict__ out,
                                     int C, int S, int opitch) {
  __shared__ float tile[64][65];
  int b = blockIdx.z;
  int s0 = blockIdx.x * 64, c0 = blockIdx.y * 64;
  const float* ip = in + (size_t)b * C * S;
  u16* op = out + (size_t)b * S * opitch;
  int tr = threadIdx.x >> 4;
  int tc4 = (threadIdx.x & 15) * 4;
#pragma unroll
  for (int r = 0; r < 64; r += 16) {
    float4 v = *(const float4*)(ip + (size_t)(c0 + tr + r) * S + s0 + tc4);
    tile[tr + r][tc4 + 0] = v.x;
    tile[tr + r][tc4 + 1] = v.y;
    tile[tr + r][tc4 + 2] = v.z;
    tile[tr + r][tc4 + 3] = v.w;
  }
  __syncthreads();
#pragma unroll
  for (int r = 0; r < 64; r += 16) {
    ushort4 v;
    v.x = f2b(tile[tc4 + 0][tr + r]);
    v.y = f2b(tile[tc4 + 1][tr + r]);
    v.z = f2b(tile[tc4 + 2][tr + r]);
    v.w = f2b(tile[tc4 + 3][tr + r]);
    *(ushort4*)(op + (size_t)(s0 + tr + r) * opitch + c0 + tc4) = v;
  }
}

// ---------------------------------------------------------------------------
// knn_scan: branchless f32 candidate scan. Grid (NCHUNK_=16, N_/256, B_)
// = 2048 blocks = 8 blocks/CU (full 32 waves/CU occupancy).
// Key = (f32 bits of d, low 8 bits cleared) | in-chunk idx (8 bits).
// Top-3/chunk via 5-op min/max network; union over chunks contains the
// exact global top-3 (quantization 2^-15 rel only reorders near-ties,
// which the f64 merge re-orders exactly).
// ---------------------------------------------------------------------------
__global__ __launch_bounds__(256) void knn_scan_kernel(
    const float* __restrict__ xyz1, const float* __restrict__ xyz2,
    u16* __restrict__ cand) {
  __shared__ float4 pts[CHS_];
  int b = blockIdx.z;
  int chunk = blockIdx.x;
  int s0 = chunk * CHS_;
  int tid = threadIdx.x;
  const float* x2 = xyz2 + ((size_t)b * S_ + s0) * 3;
  {
    float xx = x2[tid * 3], yy = x2[tid * 3 + 1], zz = x2[tid * 3 + 2];
    pts[tid] = make_float4(xx, yy, zz, fmaf(xx, xx, fmaf(yy, yy, zz * zz)));
  }
  __syncthreads();
  int n = blockIdx.y * 256 + tid;
  const float* x1 = xyz1 + ((size_t)b * N_ + n) * 3;
  float ax = x1[0], ay = x1[1], az = x1[2];
  float n1 = fmaf(ax, ax, fmaf(ay, ay, az * az));
  u32 k0 = 0xFFFFFFFFu, k1 = 0xFFFFFFFFu, k2 = 0xFFFFFFFFu;
#pragma unroll 8
  for (int s = 0; s < CHS_; ++s) {
    float4 p = pts[s];
    float dot = fmaf(ax, p.x, fmaf(ay, p.y, az * p.z));
    float d = fmaf(-2.f, dot, n1 + p.w);
    d = fmaxf(d, 0.f);
    u32 key = (__float_as_uint(d) & 0xFFFFFF00u) | (u32)s;
    u32 nk0 = min(k0, key);
    u32 nk1 = min(k1, max(k0, key));
    u32 nk2 = min(k2, max(k1, key));
    k0 = nk0; k1 = nk1; k2 = nk2;
  }
  u16* co = cand + ((size_t)(b * N_ + n)) * NCAND_ + chunk * 3;
  co[0] = (u16)((k0 & 0xFFu) + s0);
  co[1] = (u16)((k1 & 0xFFu) + s0);
  co[2] = (u16)((k2 & 0xFFu) + s0);
}

// ---------------------------------------------------------------------------
// knn_merge: per query, recompute all 48 candidate distances in f64 with the
// reference's exact formula ((n1+n2) - 2*dot, left-assoc, contract off),
// select top-3 by lexicographic (d, idx) == stable top_k semantics,
// compute interpolation weights in f64.
// ---------------------------------------------------------------------------
__global__ void knn_merge_kernel(const float* __restrict__ xyz1,
                                 const float* __restrict__ xyz2,
                                 const u16* __restrict__ cand,
                                 float* __restrict__ wout, int* __restrict__ iout) {
#pragma clang fp contract(off)
  int q = blockIdx.x * 256 + threadIdx.x;   // 0 .. B_*N_-1
  int b = q >> 14;
  const u16* ci = cand + (size_t)q * NCAND_;
  const float* x1 = xyz1 + (size_t)q * 3;
  double ax = x1[0], ay = x1[1], az = x1[2];
  double n1 = (ax * ax + ay * ay) + az * az;
  const float* x2b = xyz2 + (size_t)b * S_ * 3;
  double D0 = 1e300, D1 = 1e300, D2v = 1e300;
  int I0 = 2147483647, I1 = 2147483647, I2 = 2147483647;
  for (int j = 0; j < NCAND_; ++j) {
    int i = ci[j];
    const float* p = x2b + (size_t)i * 3;
    double px = p[0], py = p[1], pz = p[2];
    double n2 = (px * px + py * py) + pz * pz;
    double dot = (ax * px + ay * py) + az * pz;
    double d = (n1 + n2) - 2.0 * dot;
    if ((d < D2v) || (d == D2v && i < I2)) {
      if ((d < D1) || (d == D1 && i < I1)) {
        D2v = D1; I2 = I1;
        if ((d < D0) || (d == D0 && i < I0)) { D1 = D0; I1 = I0; D0 = d; I0 = i; }
        else                                  { D1 = d; I1 = i; }
      } else { D2v = d; I2 = i; }
    }
  }
  double r0 = 1.0 / (D0 + 1e-8);
  double r1 = 1.0 / (D1 + 1e-8);
  double r2 = 1.0 / (D2v + 1e-8);
  double sum = (r0 + r1) + r2;
  size_t o = (size_t)q * 3;
  wout[o + 0] = (float)(r0 / sum);
  wout[o + 1] = (float)(r1 / sum);
  wout[o + 2] = (float)(r2 / sum);
  iout[o + 0] = I0; iout[o + 1] = I1; iout[o + 2] = I2;
}

// ---------------------------------------------------------------------------
// mega: [fused interp prologue] + fuse -> ext1 -> ext2(+res) -> pred1 -> pred2
// one block = 128 points. Each wave gathers+interpolates its own 32 points
// into xbi (no barrier needed: a wave reads only its own xbi rows).
// MFMA 16x16x32 bf16; A[m=lane&15][k=(lane>>4)*8+j]; D col=lane&15, row=q*4+r
// ---------------------------------------------------------------------------
__device__ __forceinline__ void gemm_lds128(const u16* __restrict__ W, const u16* xb,
                                            int l15, int lq, int nbase, f32x4 acc[8][2]) {
#pragma unroll
  for (int mt = 0; mt < 8; ++mt) {
    acc[mt][0] = (f32x4){0.f, 0.f, 0.f, 0.f};
    acc[mt][1] = (f32x4){0.f, 0.f, 0.f, 0.f};
  }
  for (int ks = 0; ks < 4; ++ks) {
    int ko = ks * 32 + lq * 8;
    s16x8 b0 = *(const s16x8*)(xb + (nbase + l15) * 136 + ko);
    s16x8 b1 = *(const s16x8*)(xb + (nbase + 16 + l15) * 136 + ko);
#pragma unroll
    for (int mt = 0; mt < 8; ++mt) {
      s16x8 a = *(const s16x8*)(W + (size_t)(mt * 16 + l15) * 128 + ko);
      acc[mt][0] = MFMA16(a, b0, acc[mt][0]);
      acc[mt][1] = MFMA16(a, b1, acc[mt][1]);
    }
  }
}

__global__ __launch_bounds__(256) void mega_kernel(
    const u16* __restrict__ npT, const u16* __restrict__ p2t,
    const float* __restrict__ last_pred,
    const float* __restrict__ knw, const int* __restrict__ kni,
    const u16* __restrict__ Wf,
    const u16* __restrict__ W1, const u16* __restrict__ W2,
    const u16* __restrict__ W3, const u16* __restrict__ Wp2,
    const float* __restrict__ st, float* __restrict__ out) {
  __shared__ u16 xb0[128 * 136];
  __shared__ u16 xb1[128 * 136];
  __shared__ u16 xbi[128 * XBI_P];
  int b = blockIdx.y;
  int n0 = blockIdx.x * 128;
  int tid = threadIdx.x;
  int wv = tid >> 6, lane = tid & 63;
  int l15 = lane & 15, lq = lane >> 4;
  int nbase = wv * 32;
  f32x4 acc[8][2];

  // ---- prologue: gather + interpolate this wave's 32 points into xbi ----
  {
    const float* lpb = last_pred + (size_t)b * S_ * OC_;
    const u16* p2b = p2t + (size_t)b * S_ * D2_;
#pragma unroll 1
    for (int i = 0; i < 32; ++i) {
      int p = nbase + i;
      size_t o = ((size_t)(b * N_ + n0 + p)) * 3;
      float w0 = knw[o], w1 = knw[o + 1], w2 = knw[o + 2];
      int i0 = kni[o], i1 = kni[o + 1], i2 = kni[o + 2];
      ushort4 a0 = *(const ushort4*)(p2b + (size_t)i0 * D2_ + lane * 4);
      ushort4 a1 = *(const ushort4*)(p2b + (size_t)i1 * D2_ + lane * 4);
      ushort4 a2 = *(const ushort4*)(p2b + (size_t)i2 * D2_ + lane * 4);
      ushort4 v;
      v.x = f2b((w0 * b2f(a0.x) + w1 * b2f(a1.x)) + w2 * b2f(a2.x));
      v.y = f2b((w0 * b2f(a0.y) + w1 * b2f(a1.y)) + w2 * b2f(a2.y));
      v.z = f2b((w0 * b2f(a0.z) + w1 * b2f(a1.z)) + w2 * b2f(a2.z));
      v.w = f2b((w0 * b2f(a0.w) + w1 * b2f(a1.w)) + w2 * b2f(a2.w));
      *(ushort4*)(&xbi[p * XBI_P + lane * 4]) = v;
      if (lane < 32) {
        u16 pv = 0;
        if (lane < OC_) {
          pv = f2b((w0 * lpb[i0 * OC_ + lane] + w1 * lpb[i1 * OC_ + lane])
                   + w2 * lpb[i2 * OC_ + lane]);
        }
        xbi[p * XBI_P + 256 + lane] = pv;   // cols 256..287 (k=384..415)
      }
    }
  }

  // ---- stage 1: fuse (K=416): part A k<128 from npT global, part B from xbi
#pragma unroll
  for (int mt = 0; mt < 8; ++mt) {
    acc[mt][0] = (f32x4){0.f, 0.f, 0.f, 0.f};
    acc[mt][1] = (f32x4){0.f, 0.f, 0.f, 0.f};
  }
  {
    const u16* brow0 = npT + ((size_t)(b * N_ + n0 + nbase + l15)) * 128;
    const u16* brow1 = brow0 + (size_t)16 * 128;
#pragma unroll 1
    for (int ks = 0; ks < 4; ++ks) {
      int ko = ks * 32 + lq * 8;
      s16x8 bf0 = *(const s16x8*)(brow0 + ko);
      s16x8 bf1 = *(const s16x8*)(brow1 + ko);
#pragma unroll
      for (int mt = 0; mt < 8; ++mt) {
        s16x8 a = *(const s16x8*)(Wf + (size_t)(mt * 16 + l15) * KP_ + ko);
        acc[mt][0] = MFMA16(a, bf0, acc[mt][0]);
        acc[mt][1] = MFMA16(a, bf1, acc[mt][1]);
      }
    }
#pragma unroll 1
    for (int ks = 0; ks < 9; ++ks) {
      int kk = ks * 32 + lq * 8;
      s16x8 bf0 = *(const s16x8*)(&xbi[(nbase + l15) * XBI_P + kk]);
      s16x8 bf1 = *(const s16x8*)(&xbi[(nbase + 16 + l15) * XBI_P + kk]);
#pragma unroll
      for (int mt = 0; mt < 8; ++mt) {
        s16x8 a = *(const s16x8*)(Wf + (size_t)(mt * 16 + l15) * KP_ + 128 + kk);
        acc[mt][0] = MFMA16(a, bf0, acc[mt][0]);
        acc[mt][1] = MFMA16(a, bf1, acc[mt][1]);
      }
    }
  }
#pragma unroll
  for (int mt = 0; mt < 8; ++mt) {
    f32x4 sc = *(const f32x4*)(st + 0 * 256 + mt * 16 + lq * 4);
    f32x4 bi = *(const f32x4*)(st + 0 * 256 + 128 + mt * 16 + lq * 4);
#pragma unroll
    for (int nt = 0; nt < 2; ++nt) {
      int n_l = nbase + nt * 16 + l15;
      ushort4 v;
      v.x = f2b(fmaxf(acc[mt][nt][0] * sc[0] + bi[0], 0.f));
      v.y = f2b(fmaxf(acc[mt][nt][1] * sc[1] + bi[1], 0.f));
      v.z = f2b(fmaxf(acc[mt][nt][2] * sc[2] + bi[2], 0.f));
      v.w = f2b(fmaxf(acc[mt][nt][3] * sc[3] + bi[3], 0.f));
      *(ushort4*)(&xb0[n_l * 136 + mt * 16 + lq * 4]) = v;
    }
  }
  __syncthreads();

  // ---- stage 2: ext1 (K=128), xb0 -> xb1 ----
  gemm_lds128(W1, xb0, l15, lq, nbase, acc);
#pragma unroll
  for (int mt = 0; mt < 8; ++mt) {
    f32x4 sc = *(const f32x4*)(st + 1 * 256 + mt * 16 + lq * 4);
    f32x4 bi = *(const f32x4*)(st + 1 * 256 + 128 + mt * 16 + lq * 4);
#pragma unroll
    for (int nt = 0; nt < 2; ++nt) {
      int n_l = nbase + nt * 16 + l15;
      ushort4 v;
      v.x = f2b(fmaxf(acc[mt][nt][0] * sc[0] + bi[0], 0.f));
      v.y = f2b(fmaxf(acc[mt][nt][1] * sc[1] + bi[1], 0.f));
      v.z = f2b(fmaxf(acc[mt][nt][2] * sc[2] + bi[2], 0.f));
      v.w = f2b(fmaxf(acc[mt][nt][3] * sc[3] + bi[3], 0.f));
      *(ushort4*)(&xb1[n_l * 136 + mt * 16 + lq * 4]) = v;
    }
  }
  __syncthreads();

  // ---- stage 3: ext2 (K=128), xb1 -> xb0, + residual(xb0), store out0 ----
  gemm_lds128(W2, xb1, l15, lq, nbase, acc);
#pragma unroll
  for (int mt = 0; mt < 8; ++mt) {
    f32x4 sc = *(const f32x4*)(st + 2 * 256 + mt * 16 + lq * 4);
    f32x4 bi = *(const f32x4*)(st + 2 * 256 + 128 + mt * 16 + lq * 4);
#pragma unroll
    for (int nt = 0; nt < 2; ++nt) {
      int n_l = nbase + nt * 16 + l15;
      int n_g = n0 + n_l;
      ushort4 xp = *(const ushort4*)(&xb0[n_l * 136 + mt * 16 + lq * 4]);
      float v0 = fmaxf(acc[mt][nt][0] * sc[0] + bi[0] + b2f(xp.x), 0.f);
      float v1 = fmaxf(acc[mt][nt][1] * sc[1] + bi[1] + b2f(xp.y), 0.f);
      float v2 = fmaxf(acc[mt][nt][2] * sc[2] + bi[2] + b2f(xp.z), 0.f);
      float v3 = fmaxf(acc[mt][nt][3] * sc[3] + bi[3] + b2f(xp.w), 0.f);
      ushort4 v;
      v.x = f2b(v0); v.y = f2b(v1); v.z = f2b(v2); v.w = f2b(v3);
      *(ushort4*)(&xb0[n_l * 136 + mt * 16 + lq * 4]) = v;
      int m = mt * 16 + lq * 4;
      out[((size_t)(b * C_ + m + 0)) * N_ + n_g] = v0;
      out[((size_t)(b * C_ + m + 1)) * N_ + n_g] = v1;
      out[((size_t)(b * C_ + m + 2)) * N_ + n_g] = v2;
      out[((size_t)(b * C_ + m + 3)) * N_ + n_g] = v3;
    }
  }
  __syncthreads();

  // ---- stage 4: pred1 (K=128), xb0 -> xb1, store out1 ([B][N][128]) ----
  gemm_lds128(W3, xb0, l15, lq, nbase, acc);
  {
    float* out1 = out + (size_t)B_ * C_ * N_;
#pragma unroll
    for (int mt = 0; mt < 8; ++mt) {
      f32x4 sc = *(const f32x4*)(st + 3 * 256 + mt * 16 + lq * 4);
      f32x4 bi = *(const f32x4*)(st + 3 * 256 + 128 + mt * 16 + lq * 4);
#pragma unroll
      for (int nt = 0; nt < 2; ++nt) {
        int n_l = nbase + nt * 16 + l15;
        int n_g = n0 + n_l;
        float v0 = fmaxf(acc[mt][nt][0] * sc[0] + bi[0], 0.f);
        float v1 = fmaxf(acc[mt][nt][1] * sc[1] + bi[1], 0.f);
        float v2 = fmaxf(acc[mt][nt][2] * sc[2] + bi[2], 0.f);
        float v3 = fmaxf(acc[mt][nt][3] * sc[3] + bi[3], 0.f);
        ushort4 v;
        v.x = f2b(v0); v.y = f2b(v1); v.z = f2b(v2); v.w = f2b(v3);
        *(ushort4*)(&xb1[n_l * 136 + mt * 16 + lq * 4]) = v;
        float4 o4 = make_float4(v0, v1, v2, v3);
        *(float4*)(out1 + ((size_t)(b * N_ + n_g)) * 128 + mt * 16 + lq * 4) = o4;
      }
    }
  }
  __syncthreads();

  // ---- stage 5: pred2 (M=13 padded 16, K=128), xb1 -> out2 ([B][N][13]) ----
  {
    f32x4 a2[2];
    a2[0] = (f32x4){0.f, 0.f, 0.f, 0.f};
    a2[1] = (f32x4){0.f, 0.f, 0.f, 0.f};
    for (int ks = 0; ks < 4; ++ks) {
      int ko = ks * 32 + lq * 8;
      s16x8 b0 = *(const s16x8*)(&xb1[(nbase + l15) * 136 + ko]);
      s16x8 b1 = *(const s16x8*)(&xb1[(nbase + 16 + l15) * 136 + ko]);
      s16x8 a = *(const s16x8*)(Wp2 + (size_t)l15 * 128 + ko);
      a2[0] = MFMA16(a, b0, a2[0]);
      a2[1] = MFMA16(a, b1, a2[1]);
    }
    float* out2 = out + (size_t)B_ * C_ * N_ + (size_t)B_ * N_ * 128;
    f32x4 sc = *(const f32x4*)(st + 4 * 256 + lq * 4);
    f32x4 bi = *(const f32x4*)(st + 4 * 256 + 128 + lq * 4);
#pragma unroll
    for (int nt = 0; nt < 2; ++nt) {
      int n_g = n0 + nbase + nt * 16 + l15;
#pragma unroll
      for (int r = 0; r < 4; ++r) {
        int m = lq * 4 + r;
        if (m < OC_) {
          out2[((size_t)(b * N_ + n_g)) * OC_ + m] =
              fmaxf(a2[nt][r] * sc[r] + bi[r], 0.f);
        }
      }
    }
  }
}

// ---------------------------------------------------------------------------
extern "C" void kernel_launch(void* const* d_in, const int* in_sizes, int n_in,
                              void* d_out, int out_size, void* d_ws, size_t ws_size,
                              hipStream_t stream) {
  const float* xyz1      = (const float*)d_in[0];
  const float* xyz2      = (const float*)d_in[1];
  const float* points1   = (const float*)d_in[2];
  const float* points2   = (const float*)d_in[3];
  const float* last_pred = (const float*)d_in[4];
  const float* fuse_W    = (const float*)d_in[5];
  const float* fuse_b    = (const float*)d_in[6];
  const float* fuse_bn   = (const float*)d_in[7];
  const float* ext1_W    = (const float*)d_in[8];
  const float* ext1_b    = (const float*)d_in[9];
  const float* ext1_bn   = (const float*)d_in[10];
  const float* ext2_W    = (const float*)d_in[11];
  const float* ext2_b    = (const float*)d_in[12];
  const float* ext2_bn   = (const float*)d_in[13];
  const float* pred1_W   = (const float*)d_in[14];
  const float* pred1_b   = (const float*)d_in[15];
  const float* pred1_bn  = (const float*)d_in[16];
  const float* pred2_W   = (const float*)d_in[17];
  const float* pred2_b   = (const float*)d_in[18];
  const float* pred2_bn  = (const float*)d_in[19];

  char* ws = (char*)d_ws;
  u16*   npT  = (u16*)(ws + 0);                // 2*16384*128*2 =  8,388,608
  u16*   p2t  = (u16*)(ws + 8388608);          // 2*4096*256*2  =  4,194,304
  float* knw  = (float*)(ws + 12582912);       // 2*16384*3*4   =    393,216
  int*   kni  = (int*)(ws + 12976128);         //                    393,216
  u16*   cand = (u16*)(ws + 13369344);         // 2*16384*48*2  =  3,145,728
  u16*   Wf   = (u16*)(ws + 16515072);         // 128*416*2     =    106,496
  u16*   W1   = (u16*)(ws + 16621568);         // 128*128*2     =     32,768
  u16*   W2   = (u16*)(ws + 16654336);         //                     32,768
  u16*   W3   = (u16*)(ws + 16687104);         //                     32,768
  u16*   Wp2  = (u16*)(ws + 16719872);         // 16*128*2      =      4,096
  float* st   = (float*)(ws + 16723968);       // 5*256*4       =      5,120

  prep_kernel<<<dim3(64), dim3(256), 0, stream>>>(
      fuse_W, fuse_b, fuse_bn, ext1_W, ext1_b, ext1_bn, ext2_W, ext2_b, ext2_bn,
      pred1_W, pred1_b, pred1_bn, pred2_W, pred2_b, pred2_bn,
      Wf, W1, W2, W3, Wp2, st);

  // points1 [B][128][N] f32 -> npT[b][n][0..128) bf16, pitch 128
  transpose_f2b_kernel<<<dim3(N_ / 64, 128 / 64, B_), dim3(256), 0, stream>>>(
      points1, npT, 128, N_, 128);
  // points2 [B][256][S] f32 -> p2t[b][s][0..256) bf16, pitch 256
  transpose_f2b_kernel<<<dim3(S_ / 64, 256 / 64, B_), dim3(256), 0, stream>>>(
      points2, p2t, 256, S_, 256);

  knn_scan_kernel<<<dim3(NCHUNK_, N_ / 256, B_), dim3(256), 0, stream>>>(
      xyz1, xyz2, cand);
  knn_merge_kernel<<<dim3(B_ * N_ / 256), dim3(256), 0, stream>>>(
      xyz1, xyz2, cand, knw, kni);

  mega_kernel<<<dim3(N_ / 128, B_), dim3(256), 0, stream>>>(
      npT, p2t, last_pred, knw, kni, Wf, W1, W2, W3, Wp2, st, (float*)d_out);
}

// Round 6
// 236.179 us; speedup vs baseline: 1.0086x; 1.0086x over previous
//
#include <hip/hip_runtime.h>
#include <stdint.h>

#define B_   2
#define N_   16384
#define S_   4096
#define D2_  256
#define CIN_ 397
#define KP_  416      // Cin padded to 13*32 for MFMA K-slabs
#define C_   128
#define OC_  13
#define NCHUNK_ 16
#define CHS_ (S_ / NCHUNK_)       // 256 points per scan chunk
#define NCAND_ (NCHUNK_ * 3)      // 48 candidates per query
#define XBI_P 296                 // xbi LDS pitch in u16

typedef unsigned short u16;
typedef unsigned int u32;
typedef short s16x8 __attribute__((ext_vector_type(8)));
typedef float f32x4 __attribute__((ext_vector_type(4)));

#define MFMA16(a, b, c) __builtin_amdgcn_mfma_f32_16x16x32_bf16((a), (b), (c), 0, 0, 0)

__device__ __forceinline__ float b2f(u16 h) {
  union { unsigned int u; float f; } v; v.u = ((unsigned int)h) << 16; return v.f;
}
__device__ __forceinline__ u16 f2b(float f) {
  union { float f; unsigned int u; } v; v.f = f;
  unsigned int r = v.u + 0x7fffu + ((v.u >> 16) & 1u);
  return (u16)(r >> 16);
}

// ---------------------------------------------------------------------------
// setup: ONE launch doing [0,1024): transpose points1 -> npT (pitch 128),
// [1024,1536): transpose points2 -> p2t (pitch 256), [1536,1600): prep
// (weights f32->bf16 + BN fold). Cuts launch count 6 -> 4.
// ---------------------------------------------------------------------------
__device__ __forceinline__ void transpose_body(
    const float* __restrict__ in, u16* __restrict__ out,
    int C, int S, int opitch, int b, int s0, int c0,
    float (*tile)[65], int tr, int tc4) {
  const float* ip = in + (size_t)b * C * S;
  u16* op = out + (size_t)b * S * opitch;
#pragma unroll
  for (int r = 0; r < 64; r += 16) {
    float4 v = *(const float4*)(ip + (size_t)(c0 + tr + r) * S + s0 + tc4);
    tile[tr + r][tc4 + 0] = v.x;
    tile[tr + r][tc4 + 1] = v.y;
    tile[tr + r][tc4 + 2] = v.z;
    tile[tr + r][tc4 + 3] = v.w;
  }
  __syncthreads();
#pragma unroll
  for (int r = 0; r < 64; r += 16) {
    ushort4 v;
    v.x = f2b(tile[tc4 + 0][tr + r]);
    v.y = f2b(tile[tc4 + 1][tr + r]);
    v.z = f2b(tile[tc4 + 2][tr + r]);
    v.w = f2b(tile[tc4 + 3][tr + r]);
    *(ushort4*)(op + (size_t)(s0 + tr + r) * opitch + c0 + tc4) = v;
  }
}

__global__ __launch_bounds__(256) void setup_kernel(
    const float* __restrict__ points1, const float* __restrict__ points2,
    const float* __restrict__ fW, const float* __restrict__ fb,
    const float* __restrict__ fbn,
    const float* __restrict__ e1W, const float* __restrict__ e1b,
    const float* __restrict__ e1bn,
    const float* __restrict__ e2W, const float* __restrict__ e2b,
    const float* __restrict__ e2bn,
    const float* __restrict__ p1W, const float* __restrict__ p1b,
    const float* __restrict__ p1bn,
    const float* __restrict__ p2W, const float* __restrict__ p2b,
    const float* __restrict__ p2bn,
    u16* __restrict__ npT, u16* __restrict__ p2t,
    u16* __restrict__ Wf, u16* __restrict__ W1o,
    u16* __restrict__ W2o, u16* __restrict__ W3o,
    u16* __restrict__ Wp2, float* __restrict__ st) {
  __shared__ float tile[64][65];
  int id = blockIdx.x;
  int tr = threadIdx.x >> 4;
  int tc4 = (threadIdx.x & 15) * 4;
  if (id < 1024) {
    int sx = id & 255, sy = (id >> 8) & 1, b = id >> 9;
    transpose_body(points1, npT, 128, N_, 128, b, sx * 64, sy * 64, tile, tr, tc4);
    return;
  }
  if (id < 1536) {
    int id2 = id - 1024;
    int sx = id2 & 63, sy = (id2 >> 6) & 3, b = id2 >> 8;
    transpose_body(points2, p2t, 256, S_, 256, b, sx * 64, sy * 64, tile, tr, tc4);
    return;
  }
  int tid = (id - 1536) * 256 + threadIdx.x;
  int stride = 64 * 256;
  for (int i = tid; i < 128 * KP_; i += stride) {
    int m = i / KP_, k = i - m * KP_;
    Wf[i] = (k < CIN_) ? f2b(fW[m * CIN_ + k]) : (u16)0;
  }
  for (int i = tid; i < 128 * 128; i += stride) {
    W1o[i] = f2b(e1W[i]);
    W2o[i] = f2b(e2W[i]);
    W3o[i] = f2b(p1W[i]);
  }
  for (int i = tid; i < 16 * 128; i += stride) {
    int m = i >> 7;
    Wp2[i] = (m < OC_) ? f2b(p2W[i]) : (u16)0;
  }
  for (int i = tid; i < 5 * 128; i += stride) {
    int sg = i >> 7, c = i & 127;
    const float* bn; const float* bc; int Cc = 128;
    switch (sg) {
      case 0: bn = fbn;  bc = fb;  break;
      case 1: bn = e1bn; bc = e1b; break;
      case 2: bn = e2bn; bc = e2b; break;
      case 3: bn = p1bn; bc = p1b; break;
      default: bn = p2bn; bc = p2b; Cc = OC_; break;
    }
    float s = 0.f, t = 0.f;
    if (c < Cc) {
      float g  = bn[0 * Cc + c], be = bn[1 * Cc + c];
      float mu = bn[2 * Cc + c], vv = bn[3 * Cc + c];
      float inv = 1.0f / sqrtf(vv + 1e-5f);
      s = g * inv;
      t = (bc[c] - mu) * s + be;
    }
    st[sg * 256 + c] = s;
    st[sg * 256 + 128 + c] = t;
  }
}

// ---------------------------------------------------------------------------
// knn_scan: branchless f32 candidate scan (unchanged from R5).
// ---------------------------------------------------------------------------
__global__ __launch_bounds__(256) void knn_scan_kernel(
    const float* __restrict__ xyz1, const float* __restrict__ xyz2,
    u16* __restrict__ cand) {
  __shared__ float4 pts[CHS_];
  int b = blockIdx.z;
  int chunk = blockIdx.x;
  int s0 = chunk * CHS_;
  int tid = threadIdx.x;
  const float* x2 = xyz2 + ((size_t)b * S_ + s0) * 3;
  {
    float xx = x2[tid * 3], yy = x2[tid * 3 + 1], zz = x2[tid * 3 + 2];
    pts[tid] = make_float4(xx, yy, zz, fmaf(xx, xx, fmaf(yy, yy, zz * zz)));
  }
  __syncthreads();
  int n = blockIdx.y * 256 + tid;
  const float* x1 = xyz1 + ((size_t)b * N_ + n) * 3;
  float ax = x1[0], ay = x1[1], az = x1[2];
  float n1 = fmaf(ax, ax, fmaf(ay, ay, az * az));
  u32 k0 = 0xFFFFFFFFu, k1 = 0xFFFFFFFFu, k2 = 0xFFFFFFFFu;
#pragma unroll 8
  for (int s = 0; s < CHS_; ++s) {
    float4 p = pts[s];
    float dot = fmaf(ax, p.x, fmaf(ay, p.y, az * p.z));
    float d = fmaf(-2.f, dot, n1 + p.w);
    d = fmaxf(d, 0.f);
    u32 key = (__float_as_uint(d) & 0xFFFFFF00u) | (u32)s;
    u32 nk0 = min(k0, key);
    u32 nk1 = min(k1, max(k0, key));
    u32 nk2 = min(k2, max(k1, key));
    k0 = nk0; k1 = nk1; k2 = nk2;
  }
  u16* co = cand + ((size_t)(b * N_ + n)) * NCAND_ + chunk * 3;
  co[0] = (u16)((k0 & 0xFFu) + s0);
  co[1] = (u16)((k1 & 0xFFu) + s0);
  co[2] = (u16)((k2 & 0xFFu) + s0);
}

// ---------------------------------------------------------------------------
// knn_merge: f64 exact re-rank of 48 candidates. Two interleaved streams
// halve the loop-carried insert chain; final 3-element cross-insert.
// ---------------------------------------------------------------------------
__device__ __forceinline__ void ins3(double d, int i,
                                     double& D0, double& D1, double& D2,
                                     int& I0, int& I1, int& I2) {
  if ((d < D2) || (d == D2 && i < I2)) {
    if ((d < D1) || (d == D1 && i < I1)) {
      D2 = D1; I2 = I1;
      if ((d < D0) || (d == D0 && i < I0)) { D1 = D0; I1 = I0; D0 = d; I0 = i; }
      else                                  { D1 = d; I1 = i; }
    } else { D2 = d; I2 = i; }
  }
}

__global__ void knn_merge_kernel(const float* __restrict__ xyz1,
                                 const float* __restrict__ xyz2,
                                 const u16* __restrict__ cand,
                                 float* __restrict__ wout, int* __restrict__ iout) {
#pragma clang fp contract(off)
  int q = blockIdx.x * 256 + threadIdx.x;   // 0 .. B_*N_-1
  int b = q >> 14;
  const u16* ci = cand + (size_t)q * NCAND_;
  const float* x1 = xyz1 + (size_t)q * 3;
  double ax = x1[0], ay = x1[1], az = x1[2];
  double n1 = (ax * ax + ay * ay) + az * az;
  const float* x2b = xyz2 + (size_t)b * S_ * 3;
  double A0 = 1e300, A1 = 1e300, A2 = 1e300;
  int Ia0 = 2147483647, Ia1 = 2147483647, Ia2 = 2147483647;
  double Bd0 = 1e300, Bd1 = 1e300, Bd2 = 1e300;
  int Ib0 = 2147483647, Ib1 = 2147483647, Ib2 = 2147483647;
  for (int j = 0; j < NCAND_ / 2; ++j) {
    int ia = ci[2 * j], ib = ci[2 * j + 1];
    const float* pa = x2b + (size_t)ia * 3;
    const float* pb = x2b + (size_t)ib * 3;
    double pax = pa[0], pay = pa[1], paz = pa[2];
    double pbx = pb[0], pby = pb[1], pbz = pb[2];
    double na = (pax * pax + pay * pay) + paz * paz;
    double nb = (pbx * pbx + pby * pby) + pbz * pbz;
    double da = (n1 + na) - 2.0 * ((ax * pax + ay * pay) + az * paz);
    double db = (n1 + nb) - 2.0 * ((ax * pbx + ay * pby) + az * pbz);
    ins3(da, ia, A0, A1, A2, Ia0, Ia1, Ia2);
    ins3(db, ib, Bd0, Bd1, Bd2, Ib0, Ib1, Ib2);
  }
  ins3(Bd0, Ib0, A0, A1, A2, Ia0, Ia1, Ia2);
  ins3(Bd1, Ib1, A0, A1, A2, Ia0, Ia1, Ia2);
  ins3(Bd2, Ib2, A0, A1, A2, Ia0, Ia1, Ia2);
  double r0 = 1.0 / (A0 + 1e-8);
  double r1 = 1.0 / (A1 + 1e-8);
  double r2 = 1.0 / (A2 + 1e-8);
  double sum = (r0 + r1) + r2;
  size_t o = (size_t)q * 3;
  wout[o + 0] = (float)(r0 / sum);
  wout[o + 1] = (float)(r1 / sum);
  wout[o + 2] = (float)(r2 / sum);
  iout[o + 0] = Ia0; iout[o + 1] = Ia1; iout[o + 2] = Ia2;
}

// ---------------------------------------------------------------------------
// mega: 32-point tile, 1024 blocks (4 blocks/CU, 16 waves/CU).
// Waves split M: wave wv owns output rows [32wv, 32wv+32). All waves share
// the block's 32 points (N). Prologue: wave wv gathers+interpolates points
// [8wv, 8wv+8) into xbi. fuse -> ext1 -> ext2(+res) -> pred1 -> pred2.
// MFMA 16x16x32 bf16; A[m=lane&15][k=(lane>>4)*8+j]; D col=lane&15, row=q*4+r
// ---------------------------------------------------------------------------
__device__ __forceinline__ void gemm32(const u16* __restrict__ W, const u16* xb,
                                       int l15, int lq, int wv, f32x4 acc[2][2]) {
#pragma unroll
  for (int mtl = 0; mtl < 2; ++mtl) {
    acc[mtl][0] = (f32x4){0.f, 0.f, 0.f, 0.f};
    acc[mtl][1] = (f32x4){0.f, 0.f, 0.f, 0.f};
  }
#pragma unroll
  for (int ks = 0; ks < 4; ++ks) {
    int ko = ks * 32 + lq * 8;
    s16x8 b0 = *(const s16x8*)(xb + l15 * 136 + ko);
    s16x8 b1 = *(const s16x8*)(xb + (16 + l15) * 136 + ko);
#pragma unroll
    for (int mtl = 0; mtl < 2; ++mtl) {
      s16x8 a = *(const s16x8*)(W + (size_t)((wv * 2 + mtl) * 16 + l15) * 128 + ko);
      acc[mtl][0] = MFMA16(a, b0, acc[mtl][0]);
      acc[mtl][1] = MFMA16(a, b1, acc[mtl][1]);
    }
  }
}

__global__ __launch_bounds__(256, 4) void mega_kernel(
    const u16* __restrict__ npT, const u16* __restrict__ p2t,
    const float* __restrict__ last_pred,
    const float* __restrict__ knw, const int* __restrict__ kni,
    const u16* __restrict__ Wf,
    const u16* __restrict__ W1, const u16* __restrict__ W2,
    const u16* __restrict__ W3, const u16* __restrict__ Wp2,
    const float* __restrict__ st, float* __restrict__ out) {
  __shared__ u16 xb0[32 * 136];
  __shared__ u16 xb1[32 * 136];
  __shared__ u16 xbi[32 * XBI_P];
  int b = blockIdx.y;
  int n0 = blockIdx.x * 32;
  int tid = threadIdx.x;
  int wv = tid >> 6, lane = tid & 63;
  int l15 = lane & 15, lq = lane >> 4;
  f32x4 acc[2][2];

  // ---- prologue: wave wv gathers+interpolates points [8wv, 8wv+8) ----
  {
    const float* lpb = last_pred + (size_t)b * S_ * OC_;
    const u16* p2b = p2t + (size_t)b * S_ * D2_;
#pragma unroll 2
    for (int i = 0; i < 8; ++i) {
      int p = wv * 8 + i;
      size_t o = ((size_t)(b * N_ + n0 + p)) * 3;
      float w0 = knw[o], w1 = knw[o + 1], w2 = knw[o + 2];
      int i0 = kni[o], i1 = kni[o + 1], i2 = kni[o + 2];
      ushort4 a0 = *(const ushort4*)(p2b + (size_t)i0 * D2_ + lane * 4);
      ushort4 a1 = *(const ushort4*)(p2b + (size_t)i1 * D2_ + lane * 4);
      ushort4 a2 = *(const ushort4*)(p2b + (size_t)i2 * D2_ + lane * 4);
      ushort4 v;
      v.x = f2b((w0 * b2f(a0.x) + w1 * b2f(a1.x)) + w2 * b2f(a2.x));
      v.y = f2b((w0 * b2f(a0.y) + w1 * b2f(a1.y)) + w2 * b2f(a2.y));
      v.z = f2b((w0 * b2f(a0.z) + w1 * b2f(a1.z)) + w2 * b2f(a2.z));
      v.w = f2b((w0 * b2f(a0.w) + w1 * b2f(a1.w)) + w2 * b2f(a2.w));
      *(ushort4*)(&xbi[p * XBI_P + lane * 4]) = v;
      if (lane < 32) {
        u16 pv = 0;
        if (lane < OC_) {
          pv = f2b((w0 * lpb[i0 * OC_ + lane] + w1 * lpb[i1 * OC_ + lane])
                   + w2 * lpb[i2 * OC_ + lane]);
        }
        xbi[p * XBI_P + 256 + lane] = pv;   // cols 256..287 (k=384..415)
      }
    }
  }
  __syncthreads();

  // ---- stage 1: fuse (K=416): k<128 from npT (global), k>=128 from xbi ----
#pragma unroll
  for (int mtl = 0; mtl < 2; ++mtl) {
    acc[mtl][0] = (f32x4){0.f, 0.f, 0.f, 0.f};
    acc[mtl][1] = (f32x4){0.f, 0.f, 0.f, 0.f};
  }
  {
    const u16* brow0 = npT + ((size_t)(b * N_ + n0 + l15)) * 128;
    const u16* brow1 = brow0 + (size_t)16 * 128;
#pragma unroll 1
    for (int ks = 0; ks < 4; ++ks) {
      int ko = ks * 32 + lq * 8;
      s16x8 bf0 = *(const s16x8*)(brow0 + ko);
      s16x8 bf1 = *(const s16x8*)(brow1 + ko);
#pragma unroll
      for (int mtl = 0; mtl < 2; ++mtl) {
        s16x8 a = *(const s16x8*)(Wf + (size_t)((wv * 2 + mtl) * 16 + l15) * KP_ + ko);
        acc[mtl][0] = MFMA16(a, bf0, acc[mtl][0]);
        acc[mtl][1] = MFMA16(a, bf1, acc[mtl][1]);
      }
    }
#pragma unroll 1
    for (int ks = 0; ks < 9; ++ks) {
      int kk = ks * 32 + lq * 8;
      s16x8 bf0 = *(const s16x8*)(&xbi[l15 * XBI_P + kk]);
      s16x8 bf1 = *(const s16x8*)(&xbi[(16 + l15) * XBI_P + kk]);
#pragma unroll
      for (int mtl = 0; mtl < 2; ++mtl) {
        s16x8 a = *(const s16x8*)(Wf + (size_t)((wv * 2 + mtl) * 16 + l15) * KP_ + 128 + kk);
        acc[mtl][0] = MFMA16(a, bf0, acc[mtl][0]);
        acc[mtl][1] = MFMA16(a, bf1, acc[mtl][1]);
      }
    }
  }
#pragma unroll
  for (int mtl = 0; mtl < 2; ++mtl) {
    int m4 = (wv * 2 + mtl) * 16 + lq * 4;
    f32x4 sc = *(const f32x4*)(st + 0 * 256 + m4);
    f32x4 bi = *(const f32x4*)(st + 0 * 256 + 128 + m4);
#pragma unroll
    for (int nt = 0; nt < 2; ++nt) {
      int n_l = nt * 16 + l15;
      ushort4 v;
      v.x = f2b(fmaxf(acc[mtl][nt][0] * sc[0] + bi[0], 0.f));
      v.y = f2b(fmaxf(acc[mtl][nt][1] * sc[1] + bi[1], 0.f));
      v.z = f2b(fmaxf(acc[mtl][nt][2] * sc[2] + bi[2], 0.f));
      v.w = f2b(fmaxf(acc[mtl][nt][3] * sc[3] + bi[3], 0.f));
      *(ushort4*)(&xb0[n_l * 136 + m4]) = v;
    }
  }
  __syncthreads();

  // ---- stage 2: ext1 (K=128), xb0 -> xb1 ----
  gemm32(W1, xb0, l15, lq, wv, acc);
#pragma unroll
  for (int mtl = 0; mtl < 2; ++mtl) {
    int m4 = (wv * 2 + mtl) * 16 + lq * 4;
    f32x4 sc = *(const f32x4*)(st + 1 * 256 + m4);
    f32x4 bi = *(const f32x4*)(st + 1 * 256 + 128 + m4);
#pragma unroll
    for (int nt = 0; nt < 2; ++nt) {
      int n_l = nt * 16 + l15;
      ushort4 v;
      v.x = f2b(fmaxf(acc[mtl][nt][0] * sc[0] + bi[0], 0.f));
      v.y = f2b(fmaxf(acc[mtl][nt][1] * sc[1] + bi[1], 0.f));
      v.z = f2b(fmaxf(acc[mtl][nt][2] * sc[2] + bi[2], 0.f));
      v.w = f2b(fmaxf(acc[mtl][nt][3] * sc[3] + bi[3], 0.f));
      *(ushort4*)(&xb1[n_l * 136 + m4]) = v;
    }
  }
  __syncthreads();

  // ---- stage 3: ext2 (K=128), xb1 -> xb0, + residual(xb0), store out0 ----
  gemm32(W2, xb1, l15, lq, wv, acc);
#pragma unroll
  for (int mtl = 0; mtl < 2; ++mtl) {
    int m4 = (wv * 2 + mtl) * 16 + lq * 4;
    f32x4 sc = *(const f32x4*)(st + 2 * 256 + m4);
    f32x4 bi = *(const f32x4*)(st + 2 * 256 + 128 + m4);
#pragma unroll
    for (int nt = 0; nt < 2; ++nt) {
      int n_l = nt * 16 + l15;
      int n_g = n0 + n_l;
      ushort4 xp = *(const ushort4*)(&xb0[n_l * 136 + m4]);
      float v0 = fmaxf(acc[mtl][nt][0] * sc[0] + bi[0] + b2f(xp.x), 0.f);
      float v1 = fmaxf(acc[mtl][nt][1] * sc[1] + bi[1] + b2f(xp.y), 0.f);
      float v2 = fmaxf(acc[mtl][nt][2] * sc[2] + bi[2] + b2f(xp.z), 0.f);
      float v3 = fmaxf(acc[mtl][nt][3] * sc[3] + bi[3] + b2f(xp.w), 0.f);
      ushort4 v;
      v.x = f2b(v0); v.y = f2b(v1); v.z = f2b(v2); v.w = f2b(v3);
      *(ushort4*)(&xb0[n_l * 136 + m4]) = v;
      out[((size_t)(b * C_ + m4 + 0)) * N_ + n_g] = v0;
      out[((size_t)(b * C_ + m4 + 1)) * N_ + n_g] = v1;
      out[((size_t)(b * C_ + m4 + 2)) * N_ + n_g] = v2;
      out[((size_t)(b * C_ + m4 + 3)) * N_ + n_g] = v3;
    }
  }
  __syncthreads();

  // ---- stage 4: pred1 (K=128), xb0 -> xb1, store out1 ([B][N][128]) ----
  gemm32(W3, xb0, l15, lq, wv, acc);
  {
    float* out1 = out + (size_t)B_ * C_ * N_;
#pragma unroll
    for (int mtl = 0; mtl < 2; ++mtl) {
      int m4 = (wv * 2 + mtl) * 16 + lq * 4;
      f32x4 sc = *(const f32x4*)(st + 3 * 256 + m4);
      f32x4 bi = *(const f32x4*)(st + 3 * 256 + 128 + m4);
#pragma unroll
      for (int nt = 0; nt < 2; ++nt) {
        int n_l = nt * 16 + l15;
        int n_g = n0 + n_l;
        float v0 = fmaxf(acc[mtl][nt][0] * sc[0] + bi[0], 0.f);
        float v1 = fmaxf(acc[mtl][nt][1] * sc[1] + bi[1], 0.f);
        float v2 = fmaxf(acc[mtl][nt][2] * sc[2] + bi[2], 0.f);
        float v3 = fmaxf(acc[mtl][nt][3] * sc[3] + bi[3], 0.f);
        ushort4 v;
        v.x = f2b(v0); v.y = f2b(v1); v.z = f2b(v2); v.w = f2b(v3);
        *(ushort4*)(&xb1[n_l * 136 + m4]) = v;
        float4 o4 = make_float4(v0, v1, v2, v3);
        *(float4*)(out1 + ((size_t)(b * N_ + n_g)) * 128 + m4) = o4;
      }
    }
  }
  __syncthreads();

  // ---- stage 5: pred2 (M=13 pad 16, K=128): waves 0,1 each do one nt ----
  if (wv < 2) {
    f32x4 a2 = (f32x4){0.f, 0.f, 0.f, 0.f};
#pragma unroll
    for (int ks = 0; ks < 4; ++ks) {
      int ko = ks * 32 + lq * 8;
      s16x8 b0 = *(const s16x8*)(&xb1[(wv * 16 + l15) * 136 + ko]);
      s16x8 a = *(const s16x8*)(Wp2 + (size_t)l15 * 128 + ko);
      a2 = MFMA16(a, b0, a2);
    }
    float* out2 = out + (size_t)B_ * C_ * N_ + (size_t)B_ * N_ * 128;
    f32x4 sc = *(const f32x4*)(st + 4 * 256 + lq * 4);
    f32x4 bi = *(const f32x4*)(st + 4 * 256 + 128 + lq * 4);
    int n_g = n0 + wv * 16 + l15;
#pragma unroll
    for (int r = 0; r < 4; ++r) {
      int m = lq * 4 + r;
      if (m < OC_) {
        out2[((size_t)(b * N_ + n_g)) * OC_ + m] =
            fmaxf(a2[r] * sc[r] + bi[r], 0.f);
      }
    }
  }
}

// ---------------------------------------------------------------------------
extern "C" void kernel_launch(void* const* d_in, const int* in_sizes, int n_in,
                              void* d_out, int out_size, void* d_ws, size_t ws_size,
                              hipStream_t stream) {
  const float* xyz1      = (const float*)d_in[0];
  const float* xyz2      = (const float*)d_in[1];
  const float* points1   = (const float*)d_in[2];
  const float* points2   = (const float*)d_in[3];
  const float* last_pred = (const float*)d_in[4];
  const float* fuse_W    = (const float*)d_in[5];
  const float* fuse_b    = (const float*)d_in[6];
  const float* fuse_bn   = (const float*)d_in[7];
  const float* ext1_W    = (const float*)d_in[8];
  const float* ext1_b    = (const float*)d_in[9];
  const float* ext1_bn   = (const float*)d_in[10];
  const float* ext2_W    = (const float*)d_in[11];
  const float* ext2_b    = (const float*)d_in[12];
  const float* ext2_bn   = (const float*)d_in[13];
  const float* pred1_W   = (const float*)d_in[14];
  const float* pred1_b   = (const float*)d_in[15];
  const float* pred1_bn  = (const float*)d_in[16];
  const float* pred2_W   = (const float*)d_in[17];
  const float* pred2_b   = (const float*)d_in[18];
  const float* pred2_bn  = (const float*)d_in[19];

  char* ws = (char*)d_ws;
  u16*   npT  = (u16*)(ws + 0);                // 2*16384*128*2 =  8,388,608
  u16*   p2t  = (u16*)(ws + 8388608);          // 2*4096*256*2  =  4,194,304
  float* knw  = (float*)(ws + 12582912);       // 2*16384*3*4   =    393,216
  int*   kni  = (int*)(ws + 12976128);         //                    393,216
  u16*   cand = (u16*)(ws + 13369344);         // 2*16384*48*2  =  3,145,728
  u16*   Wf   = (u16*)(ws + 16515072);         // 128*416*2     =    106,496
  u16*   W1   = (u16*)(ws + 16621568);         // 128*128*2     =     32,768
  u16*   W2   = (u16*)(ws + 16654336);         //                     32,768
  u16*   W3   = (u16*)(ws + 16687104);         //                     32,768
  u16*   Wp2  = (u16*)(ws + 16719872);         // 16*128*2      =      4,096
  float* st   = (float*)(ws + 16723968);       // 5*256*4       =      5,120

  setup_kernel<<<dim3(1600), dim3(256), 0, stream>>>(
      points1, points2,
      fuse_W, fuse_b, fuse_bn, ext1_W, ext1_b, ext1_bn, ext2_W, ext2_b, ext2_bn,
      pred1_W, pred1_b, pred1_bn, pred2_W, pred2_b, pred2_bn,
      npT, p2t, Wf, W1, W2, W3, Wp2, st);

  knn_scan_kernel<<<dim3(NCHUNK_, N_ / 256, B_), dim3(256), 0, stream>>>(
      xyz1, xyz2, cand);
  knn_merge_kernel<<<dim3(B_ * N_ / 256), dim3(256), 0, stream>>>(
      xyz1, xyz2, cand, knw, kni);

  mega_kernel<<<dim3(N_ / 32, B_), dim3(256), 0, stream>>>(
      npT, p2t, last_pred, knw, kni, Wf, W1, W2, W3, Wp2, st, (float*)d_out);
}

// Round 7
// 207.691 us; speedup vs baseline: 1.1470x; 1.1372x over previous
//
#include <hip/hip_runtime.h>
#include <stdint.h>

#define B_   2
#define N_   16384
#define S_   4096
#define D2_  256
#define CIN_ 397
#define KP_  416      // Cin padded to 13*32 for MFMA K-slabs
#define C_   128
#define OC_  13
#define NCHUNK_ 16
#define CHS_ (S_ / NCHUNK_)       // 256 points per scan chunk
#define NCAND_ (NCHUNK_ * 3)      // 48 candidates per query
#define XBI_P 296                 // xbi LDS pitch in u16

typedef unsigned short u16;
typedef unsigned int u32;
typedef short s16x8 __attribute__((ext_vector_type(8)));
typedef float f32x4 __attribute__((ext_vector_type(4)));

#define MFMA16(a, b, c) __builtin_amdgcn_mfma_f32_16x16x32_bf16((a), (b), (c), 0, 0, 0)

__device__ __forceinline__ float b2f(u16 h) {
  union { unsigned int u; float f; } v; v.u = ((unsigned int)h) << 16; return v.f;
}
__device__ __forceinline__ u16 f2b(float f) {
  union { float f; unsigned int u; } v; v.f = f;
  unsigned int r = v.u + 0x7fffu + ((v.u >> 16) & 1u);
  return (u16)(r >> 16);
}

// ---------------------------------------------------------------------------
// setup_scan: ONE launch. Blocks [0,2048): knn scan (dispatched first --
// exactly 8/CU, saturates). [2048,3072): transpose points1 -> npT.
// [3072,3584): transpose points2 -> p2t. [3584,3648): weight prep + BN fold.
// ---------------------------------------------------------------------------
__device__ __forceinline__ void transpose_body(
    const float* __restrict__ in, u16* __restrict__ out,
    int C, int S, int opitch, int b, int s0, int c0,
    float* __restrict__ tile, int tr, int tc4) {
  const float* ip = in + (size_t)b * C * S;
  u16* op = out + (size_t)b * S * opitch;
#pragma unroll
  for (int r = 0; r < 64; r += 16) {
    float4 v = *(const float4*)(ip + (size_t)(c0 + tr + r) * S + s0 + tc4);
    tile[(tr + r) * 65 + tc4 + 0] = v.x;
    tile[(tr + r) * 65 + tc4 + 1] = v.y;
    tile[(tr + r) * 65 + tc4 + 2] = v.z;
    tile[(tr + r) * 65 + tc4 + 3] = v.w;
  }
  __syncthreads();
#pragma unroll
  for (int r = 0; r < 64; r += 16) {
    ushort4 v;
    v.x = f2b(tile[(tc4 + 0) * 65 + tr + r]);
    v.y = f2b(tile[(tc4 + 1) * 65 + tr + r]);
    v.z = f2b(tile[(tc4 + 2) * 65 + tr + r]);
    v.w = f2b(tile[(tc4 + 3) * 65 + tr + r]);
    *(ushort4*)(op + (size_t)(s0 + tr + r) * opitch + c0 + tc4) = v;
  }
}

__global__ __launch_bounds__(256) void setup_scan_kernel(
    const float* __restrict__ xyz1, const float* __restrict__ xyz2,
    const float* __restrict__ points1, const float* __restrict__ points2,
    const float* __restrict__ fW, const float* __restrict__ fb,
    const float* __restrict__ fbn,
    const float* __restrict__ e1W, const float* __restrict__ e1b,
    const float* __restrict__ e1bn,
    const float* __restrict__ e2W, const float* __restrict__ e2b,
    const float* __restrict__ e2bn,
    const float* __restrict__ p1W, const float* __restrict__ p1b,
    const float* __restrict__ p1bn,
    const float* __restrict__ p2W, const float* __restrict__ p2b,
    const float* __restrict__ p2bn,
    u16* __restrict__ cand, u16* __restrict__ npT, u16* __restrict__ p2t,
    u16* __restrict__ Wf, u16* __restrict__ W1o,
    u16* __restrict__ W2o, u16* __restrict__ W3o,
    u16* __restrict__ Wp2, float* __restrict__ st) {
  __shared__ __align__(16) float smem[64 * 65];
  int id = blockIdx.x;
  int tid = threadIdx.x;

  if (id < 2048) {
    // ---- knn scan: branchless f32 candidate scan, top-3/chunk ----
    float4* pts = (float4*)smem;
    int chunk = id & 15;
    int ny = (id >> 4) & 63;
    int b = id >> 10;
    int s0 = chunk * CHS_;
    const float* x2 = xyz2 + ((size_t)b * S_ + s0) * 3;
    {
      float xx = x2[tid * 3], yy = x2[tid * 3 + 1], zz = x2[tid * 3 + 2];
      pts[tid] = make_float4(xx, yy, zz, fmaf(xx, xx, fmaf(yy, yy, zz * zz)));
    }
    __syncthreads();
    int n = ny * 256 + tid;
    const float* x1 = xyz1 + ((size_t)b * N_ + n) * 3;
    float ax = x1[0], ay = x1[1], az = x1[2];
    float n1 = fmaf(ax, ax, fmaf(ay, ay, az * az));
    u32 k0 = 0xFFFFFFFFu, k1 = 0xFFFFFFFFu, k2 = 0xFFFFFFFFu;
#pragma unroll 8
    for (int s = 0; s < CHS_; ++s) {
      float4 p = pts[s];
      float dot = fmaf(ax, p.x, fmaf(ay, p.y, az * p.z));
      float d = fmaf(-2.f, dot, n1 + p.w);
      d = fmaxf(d, 0.f);
      u32 key = (__float_as_uint(d) & 0xFFFFFF00u) | (u32)s;
      u32 nk0 = min(k0, key);
      u32 nk1 = min(k1, max(k0, key));
      u32 nk2 = min(k2, max(k1, key));
      k0 = nk0; k1 = nk1; k2 = nk2;
    }
    u16* co = cand + ((size_t)(b * N_ + n)) * NCAND_ + chunk * 3;
    co[0] = (u16)((k0 & 0xFFu) + s0);
    co[1] = (u16)((k1 & 0xFFu) + s0);
    co[2] = (u16)((k2 & 0xFFu) + s0);
    return;
  }

  int tr = tid >> 4;
  int tc4 = (tid & 15) * 4;
  if (id < 3072) {
    int id2 = id - 2048;
    int sx = id2 & 255, sy = (id2 >> 8) & 1, b = id2 >> 9;
    transpose_body(points1, npT, 128, N_, 128, b, sx * 64, sy * 64, smem, tr, tc4);
    return;
  }
  if (id < 3584) {
    int id2 = id - 3072;
    int sx = id2 & 63, sy = (id2 >> 6) & 3, b = id2 >> 8;
    transpose_body(points2, p2t, 256, S_, 256, b, sx * 64, sy * 64, smem, tr, tc4);
    return;
  }
  // ---- weight prep ----
  int t = (id - 3584) * 256 + tid;
  int stride = 64 * 256;
  for (int i = t; i < 128 * KP_; i += stride) {
    int m = i / KP_, k = i - m * KP_;
    Wf[i] = (k < CIN_) ? f2b(fW[m * CIN_ + k]) : (u16)0;
  }
  for (int i = t; i < 128 * 128; i += stride) {
    W1o[i] = f2b(e1W[i]);
    W2o[i] = f2b(e2W[i]);
    W3o[i] = f2b(p1W[i]);
  }
  for (int i = t; i < 16 * 128; i += stride) {
    int m = i >> 7;
    Wp2[i] = (m < OC_) ? f2b(p2W[i]) : (u16)0;
  }
  for (int i = t; i < 5 * 128; i += stride) {
    int sg = i >> 7, c = i & 127;
    const float* bn; const float* bc; int Cc = 128;
    switch (sg) {
      case 0: bn = fbn;  bc = fb;  break;
      case 1: bn = e1bn; bc = e1b; break;
      case 2: bn = e2bn; bc = e2b; break;
      case 3: bn = p1bn; bc = p1b; break;
      default: bn = p2bn; bc = p2b; Cc = OC_; break;
    }
    float s = 0.f, tt = 0.f;
    if (c < Cc) {
      float g  = bn[0 * Cc + c], be = bn[1 * Cc + c];
      float mu = bn[2 * Cc + c], vv = bn[3 * Cc + c];
      float inv = 1.0f / sqrtf(vv + 1e-5f);
      s = g * inv;
      tt = (bc[c] - mu) * s + be;
    }
    st[sg * 256 + c] = s;
    st[sg * 256 + 128 + c] = tt;
  }
}

// ---------------------------------------------------------------------------
// f64 lexicographic (d, idx) top-3 insert -- matches stable top_k semantics
// ---------------------------------------------------------------------------
__device__ __forceinline__ void ins3(double d, int i,
                                     double& D0, double& D1, double& D2,
                                     int& I0, int& I1, int& I2) {
  if ((d < D2) || (d == D2 && i < I2)) {
    if ((d < D1) || (d == D1 && i < I1)) {
      D2 = D1; I2 = I1;
      if ((d < D0) || (d == D0 && i < I0)) { D1 = D0; I1 = I0; D0 = d; I0 = i; }
      else                                  { D1 = d; I1 = i; }
    } else { D2 = d; I2 = i; }
  }
}

// ---------------------------------------------------------------------------
// mega: [f64 merge of 48 cands] + [interp prologue] + fuse -> ext1 ->
// ext2(+res) -> pred1 -> pred2.  32-point tile, 1024 blocks, 4 blocks/CU.
// merge scratch md/mi aliases xb0/xb1 (dead until stage 1).
// MFMA 16x16x32 bf16; A[m=lane&15][k=(lane>>4)*8+j]; D col=lane&15, row=q*4+r
// ---------------------------------------------------------------------------
__device__ __forceinline__ void gemm32(const u16* __restrict__ W, const u16* xb,
                                       int l15, int lq, int wv, f32x4 acc[2][2]) {
#pragma unroll
  for (int mtl = 0; mtl < 2; ++mtl) {
    acc[mtl][0] = (f32x4){0.f, 0.f, 0.f, 0.f};
    acc[mtl][1] = (f32x4){0.f, 0.f, 0.f, 0.f};
  }
#pragma unroll
  for (int ks = 0; ks < 4; ++ks) {
    int ko = ks * 32 + lq * 8;
    s16x8 b0 = *(const s16x8*)(xb + l15 * 136 + ko);
    s16x8 b1 = *(const s16x8*)(xb + (16 + l15) * 136 + ko);
#pragma unroll
    for (int mtl = 0; mtl < 2; ++mtl) {
      s16x8 a = *(const s16x8*)(W + (size_t)((wv * 2 + mtl) * 16 + l15) * 128 + ko);
      acc[mtl][0] = MFMA16(a, b0, acc[mtl][0]);
      acc[mtl][1] = MFMA16(a, b1, acc[mtl][1]);
    }
  }
}

__global__ __launch_bounds__(256, 4) void mega_kernel(
    const float* __restrict__ xyz1, const float* __restrict__ xyz2,
    const u16* __restrict__ cand,
    const u16* __restrict__ npT, const u16* __restrict__ p2t,
    const float* __restrict__ last_pred,
    const u16* __restrict__ Wf,
    const u16* __restrict__ W1, const u16* __restrict__ W2,
    const u16* __restrict__ W3, const u16* __restrict__ Wp2,
    const float* __restrict__ st, float* __restrict__ out) {
  __shared__ __align__(16) u16 xb0[32 * 136];
  __shared__ __align__(16) u16 xb1[32 * 136];
  __shared__ u16 xbi[32 * XBI_P];
  __shared__ float wL[32][3];
  __shared__ int   iL[32][3];
  int b = blockIdx.y;
  int n0 = blockIdx.x * 32;
  int tid = threadIdx.x;
  int wv = tid >> 6, lane = tid & 63;
  int l15 = lane & 15, lq = lane >> 4;
  f32x4 acc[2][2];

  // ---- phase 0a: f64 partial top-3 (8 threads/query, 6 cands each) ----
  {
#pragma clang fp contract(off)
    double* md = (double*)xb0;   // [32][24]
    int*    mi = (int*)xb1;      // [32][24]
    int qi = tid >> 3, part = tid & 7;
    int qg = b * N_ + n0 + qi;
    const u16* ci = cand + (size_t)qg * NCAND_ + part * 6;
    const float* x1 = xyz1 + (size_t)qg * 3;
    double ax = x1[0], ay = x1[1], az = x1[2];
    double n1 = (ax * ax + ay * ay) + az * az;
    const float* x2b = xyz2 + (size_t)b * S_ * 3;
    double D0 = 1e300, D1 = 1e300, D2v = 1e300;
    int I0 = 2147483647, I1 = 2147483647, I2 = 2147483647;
#pragma unroll
    for (int j = 0; j < 6; ++j) {
      int i = ci[j];
      const float* p = x2b + (size_t)i * 3;
      double px = p[0], py = p[1], pz = p[2];
      double n2 = (px * px + py * py) + pz * pz;
      double dot = (ax * px + ay * py) + az * pz;
      double d = (n1 + n2) - 2.0 * dot;
      ins3(d, i, D0, D1, D2v, I0, I1, I2);
    }
    md[qi * 24 + part * 3 + 0] = D0; mi[qi * 24 + part * 3 + 0] = I0;
    md[qi * 24 + part * 3 + 1] = D1; mi[qi * 24 + part * 3 + 1] = I1;
    md[qi * 24 + part * 3 + 2] = D2v; mi[qi * 24 + part * 3 + 2] = I2;
  }
  __syncthreads();

  // ---- phase 0b: exact combine + weights (one thread per query) ----
  if (tid < 32) {
#pragma clang fp contract(off)
    double* md = (double*)xb0;
    int*    mi = (int*)xb1;
    double D0 = 1e300, D1 = 1e300, D2v = 1e300;
    int I0 = 2147483647, I1 = 2147483647, I2 = 2147483647;
    for (int j = 0; j < 24; ++j) {
      ins3(md[tid * 24 + j], mi[tid * 24 + j], D0, D1, D2v, I0, I1, I2);
    }
    double r0 = 1.0 / (D0 + 1e-8);
    double r1 = 1.0 / (D1 + 1e-8);
    double r2 = 1.0 / (D2v + 1e-8);
    double sum = (r0 + r1) + r2;
    wL[tid][0] = (float)(r0 / sum);
    wL[tid][1] = (float)(r1 / sum);
    wL[tid][2] = (float)(r2 / sum);
    iL[tid][0] = I0; iL[tid][1] = I1; iL[tid][2] = I2;
  }
  __syncthreads();

  // ---- prologue: wave wv gathers+interpolates points [8wv, 8wv+8) ----
  {
    const float* lpb = last_pred + (size_t)b * S_ * OC_;
    const u16* p2b = p2t + (size_t)b * S_ * D2_;
#pragma unroll 2
    for (int i = 0; i < 8; ++i) {
      int p = wv * 8 + i;
      float w0 = wL[p][0], w1 = wL[p][1], w2 = wL[p][2];
      int i0 = iL[p][0], i1 = iL[p][1], i2 = iL[p][2];
      ushort4 a0 = *(const ushort4*)(p2b + (size_t)i0 * D2_ + lane * 4);
      ushort4 a1 = *(const ushort4*)(p2b + (size_t)i1 * D2_ + lane * 4);
      ushort4 a2 = *(const ushort4*)(p2b + (size_t)i2 * D2_ + lane * 4);
      ushort4 v;
      v.x = f2b((w0 * b2f(a0.x) + w1 * b2f(a1.x)) + w2 * b2f(a2.x));
      v.y = f2b((w0 * b2f(a0.y) + w1 * b2f(a1.y)) + w2 * b2f(a2.y));
      v.z = f2b((w0 * b2f(a0.z) + w1 * b2f(a1.z)) + w2 * b2f(a2.z));
      v.w = f2b((w0 * b2f(a0.w) + w1 * b2f(a1.w)) + w2 * b2f(a2.w));
      *(ushort4*)(&xbi[p * XBI_P + lane * 4]) = v;
      if (lane < 32) {
        u16 pv = 0;
        if (lane < OC_) {
          pv = f2b((w0 * lpb[i0 * OC_ + lane] + w1 * lpb[i1 * OC_ + lane])
                   + w2 * lpb[i2 * OC_ + lane]);
        }
        xbi[p * XBI_P + 256 + lane] = pv;   // cols 256..287 (k=384..415)
      }
    }
  }
  __syncthreads();

  // ---- stage 1: fuse (K=416): k<128 from npT (global), k>=128 from xbi ----
#pragma unroll
  for (int mtl = 0; mtl < 2; ++mtl) {
    acc[mtl][0] = (f32x4){0.f, 0.f, 0.f, 0.f};
    acc[mtl][1] = (f32x4){0.f, 0.f, 0.f, 0.f};
  }
  {
    const u16* brow0 = npT + ((size_t)(b * N_ + n0 + l15)) * 128;
    const u16* brow1 = brow0 + (size_t)16 * 128;
#pragma unroll 1
    for (int ks = 0; ks < 4; ++ks) {
      int ko = ks * 32 + lq * 8;
      s16x8 bf0 = *(const s16x8*)(brow0 + ko);
      s16x8 bf1 = *(const s16x8*)(brow1 + ko);
#pragma unroll
      for (int mtl = 0; mtl < 2; ++mtl) {
        s16x8 a = *(const s16x8*)(Wf + (size_t)((wv * 2 + mtl) * 16 + l15) * KP_ + ko);
        acc[mtl][0] = MFMA16(a, bf0, acc[mtl][0]);
        acc[mtl][1] = MFMA16(a, bf1, acc[mtl][1]);
      }
    }
#pragma unroll 1
    for (int ks = 0; ks < 9; ++ks) {
      int kk = ks * 32 + lq * 8;
      s16x8 bf0 = *(const s16x8*)(&xbi[l15 * XBI_P + kk]);
      s16x8 bf1 = *(const s16x8*)(&xbi[(16 + l15) * XBI_P + kk]);
#pragma unroll
      for (int mtl = 0; mtl < 2; ++mtl) {
        s16x8 a = *(const s16x8*)(Wf + (size_t)((wv * 2 + mtl) * 16 + l15) * KP_ + 128 + kk);
        acc[mtl][0] = MFMA16(a, bf0, acc[mtl][0]);
        acc[mtl][1] = MFMA16(a, bf1, acc[mtl][1]);
      }
    }
  }
#pragma unroll
  for (int mtl = 0; mtl < 2; ++mtl) {
    int m4 = (wv * 2 + mtl) * 16 + lq * 4;
    f32x4 sc = *(const f32x4*)(st + 0 * 256 + m4);
    f32x4 bi = *(const f32x4*)(st + 0 * 256 + 128 + m4);
#pragma unroll
    for (int nt = 0; nt < 2; ++nt) {
      int n_l = nt * 16 + l15;
      ushort4 v;
      v.x = f2b(fmaxf(acc[mtl][nt][0] * sc[0] + bi[0], 0.f));
      v.y = f2b(fmaxf(acc[mtl][nt][1] * sc[1] + bi[1], 0.f));
      v.z = f2b(fmaxf(acc[mtl][nt][2] * sc[2] + bi[2], 0.f));
      v.w = f2b(fmaxf(acc[mtl][nt][3] * sc[3] + bi[3], 0.f));
      *(ushort4*)(&xb0[n_l * 136 + m4]) = v;
    }
  }
  __syncthreads();

  // ---- stage 2: ext1 (K=128), xb0 -> xb1 ----
  gemm32(W1, xb0, l15, lq, wv, acc);
#pragma unroll
  for (int mtl = 0; mtl < 2; ++mtl) {
    int m4 = (wv * 2 + mtl) * 16 + lq * 4;
    f32x4 sc = *(const f32x4*)(st + 1 * 256 + m4);
    f32x4 bi = *(const f32x4*)(st + 1 * 256 + 128 + m4);
#pragma unroll
    for (int nt = 0; nt < 2; ++nt) {
      int n_l = nt * 16 + l15;
      ushort4 v;
      v.x = f2b(fmaxf(acc[mtl][nt][0] * sc[0] + bi[0], 0.f));
      v.y = f2b(fmaxf(acc[mtl][nt][1] * sc[1] + bi[1], 0.f));
      v.z = f2b(fmaxf(acc[mtl][nt][2] * sc[2] + bi[2], 0.f));
      v.w = f2b(fmaxf(acc[mtl][nt][3] * sc[3] + bi[3], 0.f));
      *(ushort4*)(&xb1[n_l * 136 + m4]) = v;
    }
  }
  __syncthreads();

  // ---- stage 3: ext2 (K=128), xb1 -> xb0, + residual(xb0), store out0 ----
  gemm32(W2, xb1, l15, lq, wv, acc);
#pragma unroll
  for (int mtl = 0; mtl < 2; ++mtl) {
    int m4 = (wv * 2 + mtl) * 16 + lq * 4;
    f32x4 sc = *(const f32x4*)(st + 2 * 256 + m4);
    f32x4 bi = *(const f32x4*)(st + 2 * 256 + 128 + m4);
#pragma unroll
    for (int nt = 0; nt < 2; ++nt) {
      int n_l = nt * 16 + l15;
      int n_g = n0 + n_l;
      ushort4 xp = *(const ushort4*)(&xb0[n_l * 136 + m4]);
      float v0 = fmaxf(acc[mtl][nt][0] * sc[0] + bi[0] + b2f(xp.x), 0.f);
      float v1 = fmaxf(acc[mtl][nt][1] * sc[1] + bi[1] + b2f(xp.y), 0.f);
      float v2 = fmaxf(acc[mtl][nt][2] * sc[2] + bi[2] + b2f(xp.z), 0.f);
      float v3 = fmaxf(acc[mtl][nt][3] * sc[3] + bi[3] + b2f(xp.w), 0.f);
      ushort4 v;
      v.x = f2b(v0); v.y = f2b(v1); v.z = f2b(v2); v.w = f2b(v3);
      *(ushort4*)(&xb0[n_l * 136 + m4]) = v;
      out[((size_t)(b * C_ + m4 + 0)) * N_ + n_g] = v0;
      out[((size_t)(b * C_ + m4 + 1)) * N_ + n_g] = v1;
      out[((size_t)(b * C_ + m4 + 2)) * N_ + n_g] = v2;
      out[((size_t)(b * C_ + m4 + 3)) * N_ + n_g] = v3;
    }
  }
  __syncthreads();

  // ---- stage 4: pred1 (K=128), xb0 -> xb1, store out1 ([B][N][128]) ----
  gemm32(W3, xb0, l15, lq, wv, acc);
  {
    float* out1 = out + (size_t)B_ * C_ * N_;
#pragma unroll
    for (int mtl = 0; mtl < 2; ++mtl) {
      int m4 = (wv * 2 + mtl) * 16 + lq * 4;
      f32x4 sc = *(const f32x4*)(st + 3 * 256 + m4);
      f32x4 bi = *(const f32x4*)(st + 3 * 256 + 128 + m4);
#pragma unroll
      for (int nt = 0; nt < 2; ++nt) {
        int n_l = nt * 16 + l15;
        int n_g = n0 + n_l;
        float v0 = fmaxf(acc[mtl][nt][0] * sc[0] + bi[0], 0.f);
        float v1 = fmaxf(acc[mtl][nt][1] * sc[1] + bi[1], 0.f);
        float v2 = fmaxf(acc[mtl][nt][2] * sc[2] + bi[2], 0.f);
        float v3 = fmaxf(acc[mtl][nt][3] * sc[3] + bi[3], 0.f);
        ushort4 v;
        v.x = f2b(v0); v.y = f2b(v1); v.z = f2b(v2); v.w = f2b(v3);
        *(ushort4*)(&xb1[n_l * 136 + m4]) = v;
        float4 o4 = make_float4(v0, v1, v2, v3);
        *(float4*)(out1 + ((size_t)(b * N_ + n_g)) * 128 + m4) = o4;
      }
    }
  }
  __syncthreads();

  // ---- stage 5: pred2 (M=13 pad 16, K=128): waves 0,1 each do one nt ----
  if (wv < 2) {
    f32x4 a2 = (f32x4){0.f, 0.f, 0.f, 0.f};
#pragma unroll
    for (int ks = 0; ks < 4; ++ks) {
      int ko = ks * 32 + lq * 8;
      s16x8 b0 = *(const s16x8*)(&xb1[(wv * 16 + l15) * 136 + ko]);
      s16x8 a = *(const s16x8*)(Wp2 + (size_t)l15 * 128 + ko);
      a2 = MFMA16(a, b0, a2);
    }
    float* out2 = out + (size_t)B_ * C_ * N_ + (size_t)B_ * N_ * 128;
    f32x4 sc = *(const f32x4*)(st + 4 * 256 + lq * 4);
    f32x4 bi = *(const f32x4*)(st + 4 * 256 + 128 + lq * 4);
    int n_g = n0 + wv * 16 + l15;
#pragma unroll
    for (int r = 0; r < 4; ++r) {
      int m = lq * 4 + r;
      if (m < OC_) {
        out2[((size_t)(b * N_ + n_g)) * OC_ + m] =
            fmaxf(a2[r] * sc[r] + bi[r], 0.f);
      }
    }
  }
}

// ---------------------------------------------------------------------------
extern "C" void kernel_launch(void* const* d_in, const int* in_sizes, int n_in,
                              void* d_out, int out_size, void* d_ws, size_t ws_size,
                              hipStream_t stream) {
  const float* xyz1      = (const float*)d_in[0];
  const float* xyz2      = (const float*)d_in[1];
  const float* points1   = (const float*)d_in[2];
  const float* points2   = (const float*)d_in[3];
  const float* last_pred = (const float*)d_in[4];
  const float* fuse_W    = (const float*)d_in[5];
  const float* fuse_b    = (const float*)d_in[6];
  const float* fuse_bn   = (const float*)d_in[7];
  const float* ext1_W    = (const float*)d_in[8];
  const float* ext1_b    = (const float*)d_in[9];
  const float* ext1_bn   = (const float*)d_in[10];
  const float* ext2_W    = (const float*)d_in[11];
  const float* ext2_b    = (const float*)d_in[12];
  const float* ext2_bn   = (const float*)d_in[13];
  const float* pred1_W   = (const float*)d_in[14];
  const float* pred1_b   = (const float*)d_in[15];
  const float* pred1_bn  = (const float*)d_in[16];
  const float* pred2_W   = (const float*)d_in[17];
  const float* pred2_b   = (const float*)d_in[18];
  const float* pred2_bn  = (const float*)d_in[19];

  char* ws = (char*)d_ws;
  u16*   npT  = (u16*)(ws + 0);                // 2*16384*128*2 =  8,388,608
  u16*   p2t  = (u16*)(ws + 8388608);          // 2*4096*256*2  =  4,194,304
  u16*   cand = (u16*)(ws + 12582912);         // 2*16384*48*2  =  3,145,728
  u16*   Wf   = (u16*)(ws + 15728640);         // 128*416*2     =    106,496
  u16*   W1   = (u16*)(ws + 15835136);         // 128*128*2     =     32,768
  u16*   W2   = (u16*)(ws + 15867904);         //                     32,768
  u16*   W3   = (u16*)(ws + 15900672);         //                     32,768
  u16*   Wp2  = (u16*)(ws + 15933440);         // 16*128*2      =      4,096
  float* st   = (float*)(ws + 15937536);       // 5*256*4       =      5,120

  setup_scan_kernel<<<dim3(3648), dim3(256), 0, stream>>>(
      xyz1, xyz2, points1, points2,
      fuse_W, fuse_b, fuse_bn, ext1_W, ext1_b, ext1_bn, ext2_W, ext2_b, ext2_bn,
      pred1_W, pred1_b, pred1_bn, pred2_W, pred2_b, pred2_bn,
      cand, npT, p2t, Wf, W1, W2, W3, Wp2, st);

  mega_kernel<<<dim3(N_ / 32, B_), dim3(256), 0, stream>>>(
      xyz1, xyz2, cand, npT, p2t, last_pred,
      Wf, W1, W2, W3, Wp2, st, (float*)d_out);
}